// Round 12
// baseline (4925.900 us; speedup 1.0000x reference)
//
#include <hip/hip_runtime.h>

// LSTM T=16384, B=32, H=96. 32 blocks x 512 thr (8 waves, 2/SIMD). R20=4586,
// R24 revert reproduced 4580. Two models fit the 672cy step: (a) LDS-pipe
// queue ~400cy (34 LDS instrs x ~12cy; R22: +24 read-instrs -> +222cy), or
// (b) MFMA burst 350 + serial chain 320. They disagree on READ-INSTR COUNT.
// R25 (this): discriminating probe -- collapse each wave's 3 replicated
// ds_read_b128 (4-way lane replication, 192B unique) into ONE read with
// DISTINCT slices per lane: lane 16g+m (m<3) reads kt-slice m of k-group g
// at halves 8g + 32*min(rIn,2); lanes m>=3 duplicate m=2 (same-addr
// broadcast, free). 192B contiguous, <=2-way bank alias (free, m136).
// Redistribute in-register: DPP row_newbcast:m (ctrl 0x150+m, gfx90a+ --
// broadcast lane m of each 16-lane row to the row): 12 v_mov_dpp/wave
// rebuild a0/a1/a2 bit-exactly. LDS instrs/CU/step 34 -> 18; bytes 24KB->8KB.
// Cost: +12 DPP/wave issue, ~+8cy chain.
// Prediction: model (a) -> 3600-4000us; model (b) -> 4600-4800us. absmax
// bit-identical 0.015625 either way.
// Unchanged (HW-verified): B = weights cols (tile t col c -> cell
// 12wv+4t+(c>>2), gate c&3), gx in C reg0 fresh per step, te=min(h16,2)
// mirror, quad DPP tail, e_k prefold, scaled-domain c, 513-row slot-shifted
// history, one barrier/step, bulk fc flush per 512-step window.

constexpr int HH   = 96;
constexpr int BB   = 32;
constexpr int TT   = 16384;
constexpr int TH   = 512;   // 8 waves, 2 per SIMD
constexpr int NS   = 512;   // h history window
constexpr int ROWP = 104;   // halves per hist row: 208 B, 16B-aligned

typedef _Float16 f16x8 __attribute__((ext_vector_type(8)));
typedef _Float16 f16x2 __attribute__((ext_vector_type(2)));
typedef float    f32x4 __attribute__((ext_vector_type(4)));

template <int CTRL>
__device__ __forceinline__ float dpp_bcast(float v) {
    int r = __builtin_amdgcn_mov_dpp(__builtin_bit_cast(int, v), CTRL, 0xF, 0xF, true);
    return __builtin_bit_cast(float, r);
}
constexpr int DPP_B1 = 0x55;
constexpr int DPP_B2 = 0xAA;
constexpr int DPP_B3 = 0xFF;

template <int CTRL>
__device__ __forceinline__ uint32_t mvdpp(uint32_t x) {
    return (uint32_t)__builtin_amdgcn_mov_dpp((int)x, CTRL, 0xF, 0xF, true);
}
// Rebuild A-fragment for kt=M: broadcast lane M of each 16-lane row to the
// whole row (DPP row_newbcast:M = 0x150+M).
template <int M>
__device__ __forceinline__ f16x8 rowb(const uint4 v) {
    uint4 r;
    r.x = mvdpp<0x150 + M>(v.x);
    r.y = mvdpp<0x150 + M>(v.y);
    r.z = mvdpp<0x150 + M>(v.z);
    r.w = mvdpp<0x150 + M>(v.w);
    return __builtin_bit_cast(f16x8, r);
}

#define LOG2E 1.44269504f

__attribute__((amdgpu_flat_work_group_size(TH, TH)))
__global__ void lstm_kernel(const float* __restrict__ x,
                            const float* __restrict__ w_ih,
                            const float* __restrict__ w_hh,
                            const float* __restrict__ b_ih,
                            const float* __restrict__ b_hh,
                            const float* __restrict__ fc_w,
                            const float* __restrict__ fc_b,
                            float* __restrict__ out) {
    __shared__ __align__(16) _Float16 hist[(NS + 1) * ROWP];  // ~104 KB
    __shared__ __align__(16) float xs[NS];                    // 2 KB x window
    __shared__ float fcw_s[HH];

    const int tid = threadIdx.x;
    const int b   = blockIdx.x;
    const int wv  = tid >> 6;   // wave 0..7, owns cells [12wv, 12wv+12)
    const int l   = tid & 63;
    const int h16 = l >> 4;     // k-group 0..3; tail tile = min(h16,2)
    const int rIn = l & 15;     // col within tile
    const int s   = rIn & 3;    // gate 0..3 (quad lane)
    const int q   = rIn >> 2;   // cell-sub within tile
    const int te  = (h16 == 3) ? 2 : h16;    // tail tile (h16=3 mirrors 2)
    const int j   = 12 * wv + 4 * te + q;    // this lane's cell 0..95
    const int mc  = (rIn < 2) ? rIn : 2;     // which kt-slice this lane loads

    // B fragments (weights), e_k-prescaled. Tile t col rIn holds W row
    // (gate s, cell 12wv+4t+q); lane's k slice = kt*32 + 8*h16 + e.
    const float ek_s = (s == 2) ? (-2.0f * LOG2E) : (-LOG2E);
    f16x8 Bw[3][3];
#pragma unroll
    for (int t = 0; t < 3; ++t) {
        const float* wrow = w_hh + (s * HH + 12 * wv + 4 * t + q) * HH;
#pragma unroll
        for (int kt = 0; kt < 3; ++kt) {
            const float* wr = wrow + kt * 32 + 8 * h16;
            f16x8 v;
#pragma unroll
            for (int e = 0; e < 8; ++e) v[e] = (_Float16)(wr[e] * ek_s);
            Bw[t][kt] = v;
        }
    }
#pragma unroll
    for (int t = 0; t < 3; ++t)
#pragma unroll
        for (int kt = 0; kt < 3; ++kt) asm volatile("" : "+v"(Bw[t][kt]));

    const float wih2  = w_ih[s * HH + j] * ek_s;
    const float bias2 = (b_ih[s * HH + j] + b_hh[s * HH + j]) * ek_s;
    const float a_mul = (s == 2) ? (-4.0f * LOG2E) : 1.0f;
    const float a_add = (s == 2) ? (2.0f * LOG2E) : 0.0f;
    const bool  te1 = (h16 == 1), te2 = (h16 >= 2);

    const float fcb = fc_b[0];
    float c = 0.0f;   // scaled domain: c' = -2*log2e * c_true

    for (int i = tid; i < HH; i += TH) fcw_s[i] = fc_w[i];

    // Bulk fc projection for window [t0, t0+NS): h(t0+i) is in hist row i+1.
    auto flush = [&](int t0) {
        for (int i = tid; i < NS; i += TH) {
            const uint2* hr = (const uint2*)(hist + (i + 1) * ROWP);
            float a = 0.0f;
#pragma unroll
            for (int m = 0; m < 24; ++m) {
                uint2 u = hr[m];
                f16x2 p0 = __builtin_bit_cast(f16x2, u.x);
                f16x2 p1 = __builtin_bit_cast(f16x2, u.y);
                a = fmaf((float)p0.x, fcw_s[4 * m + 0], a);
                a = fmaf((float)p0.y, fcw_s[4 * m + 1], a);
                a = fmaf((float)p1.x, fcw_s[4 * m + 2], a);
                a = fmaf((float)p1.y, fcw_s[4 * m + 3], a);
            }
            out[(t0 + i) * BB + b] = a + fcb + xs[i];
        }
    };

    const _Float16* rd_q;  // per-lane gather base: 8*h16 + 32*mc; +4 rows/blk
    _Float16*       wr_p;  // h(t) cell slot base

    auto step = [&](float gx, const int ofs) {   // ofs: constant element offset
        // ONE ds_read_b128/wave: lane 16g+m fetches kt-slice m of k-group g
        // (m>=3 clamps to 2 -> same-addr broadcast). 192B unique, contiguous.
        const uint4 v = *(const uint4*)(rd_q + ofs);
        // Rebuild replicated fragments in-register (row_newbcast:m).
        const f16x8 a0 = rowb<0>(v);
        const f16x8 a1 = rowb<1>(v);
        const f16x8 a2 = rowb<2>(v);

        // C-init carries gx: lane (h16,rIn) seeds elem (row 4h16, col rIn)
        // of every tile and reads back exactly its own seed from tile te.
        const f32x4 cz = {gx, 0.f, 0.f, 0.f};
        f32x4 acc[3] = {cz, cz, cz};
        // kt-outer: 3 tile-chains interleave; C-forwarding runs at full rate.
#pragma unroll
        for (int t = 0; t < 3; ++t)
            acc[t] = __builtin_amdgcn_mfma_f32_16x16x32_f16(a0, Bw[t][0], acc[t], 0, 0, 0);
#pragma unroll
        for (int t = 0; t < 3; ++t)
            acc[t] = __builtin_amdgcn_mfma_f32_16x16x32_f16(a1, Bw[t][1], acc[t], 0, 0, 0);
#pragma unroll
        for (int t = 0; t < 3; ++t)
            acc[t] = __builtin_amdgcn_mfma_f32_16x16x32_f16(a2, Bw[t][2], acc[t], 0, 0, 0);

        // Rows are replicas -> reg 0 always; 2-cndmask tile select by te.
        float pre = te1 ? acc[1][0] : acc[0][0];
        pre       = te2 ? acc[2][0] : pre;

        const float act =
            fmaf(__builtin_amdgcn_rcpf(1.0f + __builtin_amdgcn_exp2f(pre)),
                 a_mul, a_add);
        const float fv = dpp_bcast<DPP_B1>(act);
        const float gv = dpp_bcast<DPP_B2>(act);   // already -2k-scaled
        const float ov = dpp_bcast<DPP_B3>(act);
        c = fmaf(fv, c, act * gv);                 // scaled domain
        const float rt = __builtin_amdgcn_rcpf(1.0f + __builtin_amdgcn_exp2f(c));
        const float h  = fmaf(ov + ov, rt, -ov);   // o * tanh(c_true)
        if (s == 0 && h16 < 3) *(wr_p + ofs) = (_Float16)h;
        __syncthreads();
    };

    for (int w = 0; w < TT / NS; ++w) {
        const int t0 = w * NS;
        if (w == 0) {
            if (tid < 48) ((uint32_t*)hist)[tid] = 0u;  // row 0 = h(-1) = 0
        } else {
            flush(t0 - NS);                              // old xs + rows 1..512
            if (tid < 48)                                // row 512 -> row 0
                ((uint32_t*)hist)[tid] = ((const uint32_t*)(hist + NS * ROWP))[tid];
        }
        __syncthreads();
        for (int i = tid; i < NS; i += TH) xs[i] = x[(t0 + i) * BB + b];
        __syncthreads();

        rd_q = hist + 8 * h16 + 32 * mc;
        wr_p = hist + ROWP + j;
        for (int tt = 0; tt < NS; tt += 4) {
            const float4 xq = *(const float4*)(xs + tt);  // broadcast
            const float gx0 = fmaf(xq.x, wih2, bias2);    // off-chain
            const float gx1 = fmaf(xq.y, wih2, bias2);
            const float gx2 = fmaf(xq.z, wih2, bias2);
            const float gx3 = fmaf(xq.w, wih2, bias2);
            step(gx0, 0 * ROWP);
            step(gx1, 1 * ROWP);
            step(gx2, 2 * ROWP);
            step(gx3, 3 * ROWP);
            rd_q += 4 * ROWP;
            wr_p += 4 * ROWP;
        }
    }
    flush(TT - NS);   // last window (loop ended with a barrier)
}

extern "C" void kernel_launch(void* const* d_in, const int* in_sizes, int n_in,
                              void* d_out, int out_size, void* d_ws, size_t ws_size,
                              hipStream_t stream) {
    const float* x    = (const float*)d_in[0];
    const float* w_ih = (const float*)d_in[1];
    const float* w_hh = (const float*)d_in[2];
    const float* b_ih = (const float*)d_in[3];
    const float* b_hh = (const float*)d_in[4];
    const float* fc_w = (const float*)d_in[5];
    const float* fc_b = (const float*)d_in[6];
    float* out = (float*)d_out;

    lstm_kernel<<<dim3(BB), dim3(TH), 0, stream>>>(x, w_ih, w_hh, b_ih, b_hh,
                                                   fc_w, fc_b, out);
}